// Round 8
// baseline (167.247 us; speedup 1.0000x reference)
//
#include <hip/hip_runtime.h>
#include <hip/hip_bf16.h>

#define BB   8
#define CIN  512
#define COUT 512
#define ZD   512
#define HH   64
#define WW   64

#define MOD_SCALE  0.04419417382415922f    // 1/sqrt(512)
#define CONV_SCALE 0.014731391274719742f   // 1/sqrt(512*9)

typedef __bf16 bf16x8 __attribute__((ext_vector_type(8)));
typedef float  f32x4  __attribute__((ext_vector_type(4)));
typedef float  f32x16 __attribute__((ext_vector_type(16)));

static __device__ __forceinline__ unsigned short f32_to_bf16_rne(float f) {
    unsigned int u = __float_as_uint(f);
    u = (u + 0x7FFFu + ((u >> 16) & 1u)) >> 16;
    return (unsigned short)u;
}

// ---------------- K0: sconv[b][i] = (style[b]·mod_w[i]*MOD_SCALE + mod_b[i]) * CONV_SCALE
__global__ void k_style(const float* __restrict__ style, const float* __restrict__ mod_w,
                        const float* __restrict__ mod_b, float* __restrict__ sconv) {
    int wid  = blockIdx.x * 4 + (threadIdx.x >> 6);   // 0..4095 = b*512+i
    int lane = threadIdx.x & 63;
    int b = wid >> 9;
    int i = wid & 511;
    const float4* st = (const float4*)(style + (size_t)b * ZD);
    const float4* mw = (const float4*)(mod_w + (size_t)i * ZD);
    float4 a0 = st[lane],      b0 = mw[lane];
    float4 a1 = st[lane + 64], b1 = mw[lane + 64];
    float sum = a0.x*b0.x + a0.y*b0.y + a0.z*b0.z + a0.w*b0.w
              + a1.x*b1.x + a1.y*b1.y + a1.z*b1.z + a1.w*b1.w;
    #pragma unroll
    for (int off = 32; off > 0; off >>= 1) sum += __shfl_down(sum, off);
    if (lane == 0) sconv[wid] = (sum * MOD_SCALE + mod_b[i]) * CONV_SCALE;
}

// ---------------- K1: zero the 1-px border of padded xs2p [8][66][66][512] bf16
__global__ void k_zero_border(unsigned short* __restrict__ xs2p) {
    int b = blockIdx.y;
    int p = blockIdx.x * 4 + (threadIdx.x >> 6);   // 0..259
    int lane = threadIdx.x & 63;
    int h, w;
    if (p < 66)       { h = 0;       w = p; }
    else if (p < 132) { h = 65;      w = p - 66; }
    else if (p < 196) { h = p - 131; w = 0; }      // rows 1..64
    else              { h = p - 195; w = 65; }
    int4 z = {0, 0, 0, 0};
    *(int4*)&xs2p[((size_t)(b * 66 + h) * 66 + w) * 512 + lane * 8] = z;
}

// ---------------- K2: xs2p[b][h+1][w+1][i] = bf16(input[b][i][h][w] * sconv[b][i])
__global__ void k_scale_input(const float* __restrict__ input, const float* __restrict__ sconv,
                              unsigned short* __restrict__ xs2p) {
    int i0 = blockIdx.x * 32;
    int h  = blockIdx.y;
    int b  = blockIdx.z;
    __shared__ unsigned short lds[64][40];   // [w][ii], padded row
    #pragma unroll
    for (int r = 0; r < 8; ++r) {
        int ii = r * 4 + (threadIdx.x >> 6);
        int w  = threadIdx.x & 63;
        float v = input[(((size_t)b * CIN + i0 + ii) * HH + h) * WW + w];
        float s = sconv[b * CIN + i0 + ii];
        lds[w][ii] = f32_to_bf16_rne(v * s);
    }
    __syncthreads();
    int w = threadIdx.x >> 2, q = threadIdx.x & 3;
    int4 val = *(const int4*)&lds[w][q * 8];
    *(int4*)&xs2p[((size_t)(b * 66 + h + 1) * 66 + (w + 1)) * 512 + i0 + q * 8] = val;
}

// ---------------- K3: w3 ts-linear weights. ts = c*9+tap.
// byte addr = ts*32768 + half*16384 + (g*256 + oc_low)*16 ; elem += i&7
__global__ void k_weight(const float* __restrict__ weight, unsigned short* __restrict__ w3) {
    int t = blockIdx.x * 256 + threadIdx.x;   // 0 .. 512*512-1 : o*512 + i
    int o = t >> 9, i = t & 511;
    int c = i >> 5, g = (i >> 3) & 3, il = i & 7;
    int h = o >> 8, ol = o & 255;
    const float* src = weight + ((size_t)o * CIN + i) * 9;
    #pragma unroll
    for (int p = 0; p < 9; ++p) {
        size_t gran = ((size_t)(c * 9 + p) * 2 + h) * 1024 + g * 256 + ol;
        w3[gran * 8 + il] = f32_to_bf16_rne(src[p]);
    }
}

// ---------------- K4: main conv. 512 thr / 8 waves. Block tile 256 OC x (4 rows x 64 px).
// Wave tile 64 oc x 128 px (mt2 x nt4). W: global->VGPR direct (ts-linear w3, E/O
// double-buffer, per-wave waits). X: LDS 2x32KB, staged per 9-tap chunk; ONE barrier
// per chunk. DS traffic 8 reads/wave/ts -> LDS pipe (~800cyc/CU) < MFMA (1033cyc).
#define GLD(srcp, ldsbyte)                                                        \
    __builtin_amdgcn_global_load_lds(                                             \
        (const __attribute__((address_space(1))) unsigned int*)(srcp),            \
        (__attribute__((address_space(3))) unsigned int*)(smb + (ldsbyte)),       \
        16, 0, 0)

#define TAP(t, DOX, DOW, ENDCH, C, N) {                                           \
    if (DOW) {                                                                    \
        aW##N[0][0] = *(const bf16x8*)(pA);                                       \
        aW##N[1][0] = *(const bf16x8*)(pA + 512);                                 \
        aW##N[0][1] = *(const bf16x8*)(pA + 8192);                                \
        aW##N[1][1] = *(const bf16x8*)(pA + 8704);                                \
        pA += 32768;                                                              \
    }                                                                             \
    if ((DOX) && (t) == 0) { GLD(sxn +  0, xwr + 0 * 8192 + wdst);                \
                             GLD(sxn + 16, xwr + 1 * 8192 + wdst); }              \
    if ((DOX) && (t) == 1) { GLD(sxn + 32, xwr + 2 * 8192 + wdst);                \
                             GLD(sxn + 48, xwr + 3 * 8192 + wdst); }              \
    {   const int kh_ = (t) / 3, kw_ = (t) % 3;                                   \
        const char* xb = smb + xrd + boff + (kh_ * 66 + kw_) * 16;                \
        bfr[0][0] = *(const bf16x8*)(xb);                                         \
        bfr[1][0] = *(const bf16x8*)(xb + 512);                                   \
        bfr[2][0] = *(const bf16x8*)(xb + 1056);                                  \
        bfr[3][0] = *(const bf16x8*)(xb + 1568);                                  \
        bfr[0][1] = *(const bf16x8*)(xb + 16384);                                 \
        bfr[1][1] = *(const bf16x8*)(xb + 16896);                                 \
        bfr[2][1] = *(const bf16x8*)(xb + 17440);                                 \
        bfr[3][1] = *(const bf16x8*)(xb + 17952);                                 \
    }                                                                             \
    __builtin_amdgcn_s_setprio(1);                                                \
    _Pragma("unroll") for (int h = 0; h < 2; ++h)                                 \
      _Pragma("unroll") for (int mt = 0; mt < 2; ++mt)                            \
        _Pragma("unroll") for (int nt = 0; nt < 4; ++nt)                          \
            acc[mt][nt] = __builtin_amdgcn_mfma_f32_32x32x16_bf16(                \
                aW##C[mt][h], bfr[nt][h], acc[mt][nt], 0, 0, 0);                  \
    __builtin_amdgcn_s_setprio(0);                                                \
    if (ENDCH) { asm volatile("s_waitcnt vmcnt(4)" ::: "memory");                 \
                 __builtin_amdgcn_s_barrier(); xrd ^= 32768; sxn += 64; }         \
}

// full chunk starting on E parity (chunks 0,2,..,14): stages X(c+1), prefetches W
#define CHUNKE_FULL {                                                             \
    const int xwr = xrd ^ 32768;                                                  \
    TAP(0, 1, 1, 0, E, O) TAP(1, 1, 1, 0, O, E) TAP(2, 0, 1, 0, E, O)             \
    TAP(3, 0, 1, 0, O, E) TAP(4, 0, 1, 0, E, O) TAP(5, 0, 1, 0, O, E)             \
    TAP(6, 0, 1, 0, E, O) TAP(7, 0, 1, 0, O, E) TAP(8, 0, 1, 1, E, O) }
// full chunk starting on O parity (chunks 1,3,..,13)
#define CHUNKO_FULL {                                                             \
    const int xwr = xrd ^ 32768;                                                  \
    TAP(0, 1, 1, 0, O, E) TAP(1, 1, 1, 0, E, O) TAP(2, 0, 1, 0, O, E)             \
    TAP(3, 0, 1, 0, E, O) TAP(4, 0, 1, 0, O, E) TAP(5, 0, 1, 0, E, O)             \
    TAP(6, 0, 1, 0, O, E) TAP(7, 0, 1, 0, E, O) TAP(8, 0, 1, 1, O, E) }
// tail chunk 15 (starts O): no X stage, last W load at tap7 (ts143), no barrier
#define CHUNKO_TAIL {                                                             \
    const int xwr = 0; (void)xwr;                                                 \
    TAP(0, 0, 1, 0, O, E) TAP(1, 0, 1, 0, E, O) TAP(2, 0, 1, 0, O, E)             \
    TAP(3, 0, 1, 0, E, O) TAP(4, 0, 1, 0, O, E) TAP(5, 0, 1, 0, E, O)             \
    TAP(6, 0, 1, 0, O, E) TAP(7, 0, 1, 0, E, O) TAP(8, 0, 0, 0, O, E) }

__global__ __launch_bounds__(512, 2)
void k_conv(const unsigned short* __restrict__ xs2p, const unsigned short* __restrict__ w3,
            float* __restrict__ out) {
    __shared__ unsigned short smem[32768];   // 65536 bytes: X double buffer only
    char* smb = (char*)smem;

    const int tid  = threadIdx.x;
    const int wid  = tid >> 6, lane = tid & 63;
    const int wm4  = wid >> 1, wr2  = wid & 1;    // oc quarter / row pair
    const int l31  = lane & 31, l5  = lane >> 5;
    const int half = blockIdx.x;                  // 0,1 -> oc0 = half*256
    const int oc0  = half * 256;
    const int y0   = blockIdx.y * 4;
    const int b    = blockIdx.z;

    const int p_lin = wid * 64 + lane;            // 0..511
    const int xrow  = p_lin / 66;
    const int xcol  = p_lin - xrow * 66;
    const char* srcX = (const char*)xs2p;
    if (p_lin < 396)
        srcX += ((size_t)(b * 66 + y0 + xrow) * 66 + xcol) * 1024;  // 1KB per pixel

    // per-lane W source: ts*32768 + half*16384 + ((2h+l5)*256 + wm4*64 + mt*32 + l31)*16
    const char* pA = (const char*)w3 + (size_t)half * 16384
                   + ((size_t)(l5 * 256 + wm4 * 64 + l31)) * 16;
    const int wdst = p_lin * 16;                  // wave-linear LDS slice

    // ---- prologue: X(0) into buf0, W(ts0) into E regs
    GLD(srcX +  0, 0 * 8192 + wdst);
    GLD(srcX + 16, 1 * 8192 + wdst);
    GLD(srcX + 32, 2 * 8192 + wdst);
    GLD(srcX + 48, 3 * 8192 + wdst);
    bf16x8 aWE[2][2], aWO[2][2], bfr[4][2];
    aWE[0][0] = *(const bf16x8*)(pA);
    aWE[1][0] = *(const bf16x8*)(pA + 512);
    aWE[0][1] = *(const bf16x8*)(pA + 8192);
    aWE[1][1] = *(const bf16x8*)(pA + 8704);
    pA += 32768;                                  // -> W(ts1)
    asm volatile("s_waitcnt vmcnt(4)" ::: "memory");  // X(0) landed; W(0) may be in flight
    __builtin_amdgcn_s_barrier();

    f32x16 acc[2][4];
    #pragma unroll
    for (int mt = 0; mt < 2; ++mt)
        #pragma unroll
        for (int nt = 0; nt < 4; ++nt)
            acc[mt][nt] = (f32x16)(0.f);

    // X frag base: plane l5, row pair 2*wr2, px l31
    const int boff = l5 * 8192 + (wr2 * 2 * 66 + l31) * 16;

    int xrd = 0;                                  // X read buffer byte offset
    const char* sxn = srcX + 64;                  // next chunk's source (c=1)

    for (int c2 = 0; c2 < 7; ++c2) {
        CHUNKE_FULL   // even chunk
        CHUNKO_FULL   // odd chunk
    }
    CHUNKE_FULL       // chunk 14 (stages X(15))
    CHUNKO_TAIL       // chunk 15

    // ---- epilogue: 32x32 C/D: col(px)=lane&31, row(oc)=(r&3)+8*(r>>2)+4*l5
    #pragma unroll
    for (int mt = 0; mt < 2; ++mt)
        #pragma unroll
        for (int nt = 0; nt < 4; ++nt) {
            const int y  = y0 + wr2 * 2 + (nt >> 1);
            const int px = (nt & 1) * 32 + l31;
            #pragma unroll
            for (int r = 0; r < 16; ++r) {
                int row = (r & 3) + 8 * (r >> 2) + 4 * l5;
                int oc  = oc0 + wm4 * 64 + mt * 32 + row;
                out[((size_t)(b * COUT + oc) << 12) + y * 64 + px] = acc[mt][nt][r];
            }
        }
}

extern "C" void kernel_launch(void* const* d_in, const int* in_sizes, int n_in,
                              void* d_out, int out_size, void* d_ws, size_t ws_size,
                              hipStream_t stream) {
    const float* input  = (const float*)d_in[0];
    const float* style  = (const float*)d_in[1];
    const float* weight = (const float*)d_in[2];
    const float* mod_w  = (const float*)d_in[3];
    const float* mod_b  = (const float*)d_in[4];
    float* out = (float*)d_out;

    const size_t xs2p_bytes = (size_t)BB * 66 * 66 * 512 * 2;   // 35,684,352
    const size_t w3_bytes   = (size_t)144 * 2 * 1024 * 8 * 2;   // 4,718,592
    const size_t need = 16384 + xs2p_bytes + w3_bytes;
    if (ws_size < need) return;   // leave output poisoned -> clear failure

    float*          sconv = (float*)d_ws;
    unsigned short* xs2p  = (unsigned short*)((char*)d_ws + 16384);
    unsigned short* w3    = (unsigned short*)((char*)d_ws + 16384 + xs2p_bytes);

    hipLaunchKernelGGL(k_style,       dim3(1024),      dim3(256), 0, stream, style, mod_w, mod_b, sconv);
    hipLaunchKernelGGL(k_weight,      dim3(1024),      dim3(256), 0, stream, weight, w3);
    hipLaunchKernelGGL(k_zero_border, dim3(65, 8),     dim3(256), 0, stream, xs2p);
    hipLaunchKernelGGL(k_scale_input, dim3(16, 64, 8), dim3(256), 0, stream, input, sconv, xs2p);
    hipLaunchKernelGGL(k_conv,        dim3(2, 16, 8),  dim3(512), 0, stream, xs2p, w3, out);
}